// Round 7
// baseline (298.883 us; speedup 1.0000x reference)
//
#include <hip/hip_runtime.h>
#include <hip/hip_bf16.h>

typedef __attribute__((ext_vector_type(8))) short bf16x8;
typedef __attribute__((ext_vector_type(4))) short s16x4;
typedef __attribute__((ext_vector_type(4))) float f32x4;

#define NTOK 49

// LDS (shorts), total 24384 = 48768 B -> 3 blocks/CU:
//  vbt: head h at h*2176: V^T [32][68]  (toks 49..63 zeroed once)
//  RQK = 8704: head h at RQK + h*3920:  q[49][40], k[49][40] at +1960
//    pbuf [49][72] overlays q+k after B3 (rows private per wave);
//    O_h[qtok][dim0..31] reuses pbuf rows, cols 0..31 (written after own PV)
#define VBT_STR 68
#define VBT_SZ  2176
#define RQK     8704
#define QK_SZ   3920
#define SM_TOT  24384

__device__ __forceinline__ short f2b(float v) {
    __hip_bfloat16 b = __float2bfloat16(v);
    return *reinterpret_cast<short*>(&b);
}

__device__ __forceinline__ bf16x8 cvt8(f32x4 a, f32x4 b) {
    bf16x8 r;
    r[0]=f2b(a[0]); r[1]=f2b(a[1]); r[2]=f2b(a[2]); r[3]=f2b(a[3]);
    r[4]=f2b(b[0]); r[5]=f2b(b[1]); r[6]=f2b(b[2]); r[7]=f2b(b[3]);
    return r;
}

// region id: mask[w][i][j]==0 iff rid(i)==rid(j); slices [0,49)[49,53)[53,56)
__device__ __forceinline__ int rid_of(int t, int wh, int ww) {
    int i = t / 7;
    int j = t - 7 * i;
    int rh = (wh == 7) ? ((i < 4) ? 1 : 2) : 0;
    int rw = (ww == 7) ? ((j < 4) ? 1 : 2) : 0;
    return rh * 3 + rw;
}

__global__ void prep_kernel(const float* __restrict__ qkv_w,
                            const float* __restrict__ proj_w,
                            const float* __restrict__ rel_tab,
                            const int*   __restrict__ rel_idx,
                            short* __restrict__ wqkv_t,
                            short* __restrict__ wproj_t,
                            float* __restrict__ bmp2) {
    int i = blockIdx.x * 256 + threadIdx.x;
    if (i < 384 * 128) {               // wqkv_t[n][k] = qkv_w[k][n]
        int n = i >> 7, k = i & 127;
        wqkv_t[i] = f2b(qkv_w[k * 384 + n]);
        return;
    }
    int j = i - 384 * 128;
    if (j < 128 * 128) {               // wproj_t[n][k] = proj_w[k][n]
        int n = j >> 7, k = j & 127;
        wproj_t[j] = f2b(proj_w[k * 128 + n]);
        return;
    }
    int l = j - 128 * 128;
    if (l < 16 * NTOK * 64) {          // bmp2[wt][h][q][k64]: bias + mask, pad -1e30
        int wt  = l / (4 * NTOK * 64);
        int rem = l - wt * (4 * NTOK * 64);
        int h   = rem / (NTOK * 64);
        int rm2 = rem - h * (NTOK * 64);
        int q = rm2 >> 6, kk = rm2 & 63;
        float v;
        if (kk < NTOK) {
            v = rel_tab[rel_idx[q * NTOK + kk] * 4 + h];
            int wh = (wt & 1) ? 7 : 0, ww = (wt & 2) ? 7 : 0;
            if (rid_of(q, wh, ww) != rid_of(kk, wh, ww)) v -= 100.0f;
        } else {
            v = -1e30f;
        }
        bmp2[l] = v;
    }
}

__launch_bounds__(512, 6)
__global__ void swin_fused(const float* __restrict__ x,
                           const short* __restrict__ wqkv_t,
                           const float* __restrict__ qkv_b,
                           const short* __restrict__ wproj_t,
                           const float* __restrict__ proj_b,
                           const float* __restrict__ bmp2,
                           float* __restrict__ out) {
    __shared__ short sm[SM_TOT];

    const int b   = blockIdx.x;
    const int tid = threadIdx.x;
    const int wv  = tid >> 6;
    const int ln  = tid & 63;
    const int g   = ln >> 4;
    const int c   = ln & 15;
    const int h    = wv >> 1;
    const int half = wv & 1;

    short* vbt = sm + h * VBT_SZ;            // [32][68]
    short* qbh = sm + RQK + h * QK_SZ;       // [49][40]
    short* kbh = qbh + 1960;                 // [49][40]
    short* pbh = qbh;                        // [49][72] overlay (post-B3); O in cols 0..31

    // zero V^T pad toks 49..63 for all 128 dims (before any PV read)
    for (int idx = tid; idx < 128 * 15; idx += 512) {
        int d = idx / 15, t = 49 + (idx - (idx / 15) * 15);
        sm[(d >> 5) * VBT_SZ + (d & 31) * VBT_STR + t] = 0;
    }

    const float* xw = x + (size_t)b * 6272;
    const int cq = 32 * h + 16 * half;       // wave's 16-channel base
    int tokn[4];
    #pragma unroll
    for (int nt = 0; nt < 4; ++nt) { int t = 16*nt + c; tokn[nt] = (t > 48) ? 48 : t; }

    // ---------- phase 1a: Q,K channels [cq,cq+16), X read direct from global ----------
    {
        f32x4 accq[4], acck[4];
        #pragma unroll
        for (int nt = 0; nt < 4; ++nt) { accq[nt] = (f32x4){0.f,0.f,0.f,0.f}; acck[nt] = (f32x4){0.f,0.f,0.f,0.f}; }
        #pragma unroll
        for (int kt = 0; kt < 4; ++kt) {
            bf16x8 awq = *(const bf16x8*)&wqkv_t[(cq + c) * 128 + 32*kt + 8*g];
            bf16x8 awk = *(const bf16x8*)&wqkv_t[(128 + cq + c) * 128 + 32*kt + 8*g];
            bf16x8 xv[4];
            #pragma unroll
            for (int nt = 0; nt < 4; ++nt) {
                const float* p = xw + tokn[nt] * 128 + 32*kt + 8*g;
                xv[nt] = cvt8(*(const f32x4*)p, *(const f32x4*)(p + 4));
            }
            __builtin_amdgcn_s_setprio(1);
            #pragma unroll
            for (int nt = 0; nt < 4; ++nt) {
                accq[nt] = __builtin_amdgcn_mfma_f32_16x16x32_bf16(awq, xv[nt], accq[nt], 0, 0, 0);
                acck[nt] = __builtin_amdgcn_mfma_f32_16x16x32_bf16(awk, xv[nt], acck[nt], 0, 0, 0);
            }
            __builtin_amdgcn_s_setprio(0);
        }
        const float qsc = 0.17677669529663687f;   // 32^-0.5 folded into q
        f32x4 bq4 = *(const f32x4*)&qkv_b[cq + 4*g];
        f32x4 bk4 = *(const f32x4*)&qkv_b[128 + cq + 4*g];
        #pragma unroll
        for (int nt = 0; nt < 4; ++nt) {
            int tok = 16*nt + c;
            if (tok >= NTOK) continue;
            s16x4 pq, pk2;
            #pragma unroll
            for (int r = 0; r < 4; ++r) {
                pq[r]  = f2b((accq[nt][r] + bq4[r]) * qsc);
                pk2[r] = f2b(acck[nt][r] + bk4[r]);
            }
            *(s16x4*)&qbh[tok * 40 + 16*half + 4*g] = pq;
            *(s16x4*)&kbh[tok * 40 + 16*half + 4*g] = pk2;
        }
    }

    // ---------- phase 1b: V channels -> vbt (X re-read, cache-hot) ----------
    {
        f32x4 accv[4];
        #pragma unroll
        for (int nt = 0; nt < 4; ++nt) accv[nt] = (f32x4){0.f,0.f,0.f,0.f};
        #pragma unroll
        for (int kt = 0; kt < 4; ++kt) {
            bf16x8 awv = *(const bf16x8*)&wqkv_t[(256 + cq + c) * 128 + 32*kt + 8*g];
            bf16x8 xv[4];
            #pragma unroll
            for (int nt = 0; nt < 4; ++nt) {
                const float* p = xw + tokn[nt] * 128 + 32*kt + 8*g;
                xv[nt] = cvt8(*(const f32x4*)p, *(const f32x4*)(p + 4));
            }
            __builtin_amdgcn_s_setprio(1);
            #pragma unroll
            for (int nt = 0; nt < 4; ++nt)
                accv[nt] = __builtin_amdgcn_mfma_f32_16x16x32_bf16(awv, xv[nt], accv[nt], 0, 0, 0);
            __builtin_amdgcn_s_setprio(0);
        }
        f32x4 bv4 = *(const f32x4*)&qkv_b[256 + cq + 4*g];
        const int d0 = 16*half + 4*g;
        #pragma unroll
        for (int nt = 0; nt < 4; ++nt) {
            int tok = 16*nt + c;
            if (tok >= NTOK) continue;
            vbt[(d0+0) * VBT_STR + tok] = f2b(accv[nt][0] + bv4[0]);
            vbt[(d0+1) * VBT_STR + tok] = f2b(accv[nt][1] + bv4[1]);
            vbt[(d0+2) * VBT_STR + tok] = f2b(accv[nt][2] + bv4[2]);
            vbt[(d0+3) * VBT_STR + tok] = f2b(accv[nt][3] + bv4[3]);
        }
    }
    __syncthreads();   // B2: q,k,v^T ready

    // ---------- phase 2: S^T = K(64x32) @ Q^T(32x64) ----------
    const int ntq0 = 2 * half;
    f32x4 sA[4][2];
    {
        #pragma unroll
        for (int mt = 0; mt < 4; ++mt) { sA[mt][0] = (f32x4){0.f,0.f,0.f,0.f}; sA[mt][1] = (f32x4){0.f,0.f,0.f,0.f}; }
        bf16x8 ak[4];
        #pragma unroll
        for (int mt = 0; mt < 4; ++mt) {
            int kt2 = 16*mt + c; if (kt2 > 48) kt2 = 48;
            ak[mt] = *(const bf16x8*)&kbh[kt2 * 40 + 8*g];
        }
        __builtin_amdgcn_s_setprio(1);
        #pragma unroll
        for (int jj = 0; jj < 2; ++jj) {
            int qt = 16*(ntq0+jj) + c; if (qt > 48) qt = 48;
            bf16x8 bq = *(const bf16x8*)&qbh[qt * 40 + 8*g];
            #pragma unroll
            for (int mt = 0; mt < 4; ++mt)
                sA[mt][jj] = __builtin_amdgcn_mfma_f32_16x16x32_bf16(ak[mt], bq, sA[mt][jj], 0, 0, 0);
        }
        __builtin_amdgcn_s_setprio(0);
    }
    __syncthreads();   // B3: q,k fragments consumed; pbuf may overlay

    // ---------- softmax (mask folded into bmp2) + P -> pbuf + PV + O -> pbuf cols 0..31 ----------
    {
        const int wt = ((((b >> 3) & 7) == 7) ? 1 : 0) | (((b & 7) == 7) ? 2 : 0);
        const float* bbase = bmp2 + ((size_t)(wt * 4 + h) * NTOK) * 64;
        #pragma unroll
        for (int jj = 0; jj < 2; ++jj) {
            int qtok = 16*(ntq0+jj) + c;
            int qtokc = qtok > 48 ? 48 : qtok;
            const float* bp = bbase + (size_t)qtokc * 64;
            float e[16];
            float mx = -1e30f;
            #pragma unroll
            for (int mt = 0; mt < 4; ++mt) {
                f32x4 b4 = *(const f32x4*)&bp[16*mt + 4*g];
                #pragma unroll
                for (int r = 0; r < 4; ++r) {
                    float v = sA[mt][jj][r] + b4[r];
                    e[4*mt+r] = v;
                    mx = fmaxf(mx, v);
                }
            }
            mx = fmaxf(mx, __shfl_xor(mx, 16, 64));
            mx = fmaxf(mx, __shfl_xor(mx, 32, 64));
            float s = 0.f;
            #pragma unroll
            for (int ii = 0; ii < 16; ++ii) { float ev = __expf(e[ii] - mx); e[ii] = ev; s += ev; }
            s += __shfl_xor(s, 16, 64);
            s += __shfl_xor(s, 32, 64);
            float rs = 1.0f / s;
            if (qtok < NTOK) {
                #pragma unroll
                for (int mt = 0; mt < 4; ++mt) {
                    s16x4 pk;
                    pk[0] = f2b(e[4*mt+0] * rs);
                    pk[1] = f2b(e[4*mt+1] * rs);
                    pk[2] = f2b(e[4*mt+2] * rs);
                    pk[3] = f2b(e[4*mt+3] * rs);
                    *(s16x4*)&pbh[qtok * 72 + 16*mt + 4*g] = pk;
                }
            }
        }

        // PV: O^T = V^T(32x64) @ P^T(64x64); P pad rows (k>=49) are -inf -> exp 0
        f32x4 o[2][2];
        o[0][0]=(f32x4){0.f,0.f,0.f,0.f}; o[0][1]=(f32x4){0.f,0.f,0.f,0.f};
        o[1][0]=(f32x4){0.f,0.f,0.f,0.f}; o[1][1]=(f32x4){0.f,0.f,0.f,0.f};
        __builtin_amdgcn_s_setprio(1);
        #pragma unroll
        for (int kt = 0; kt < 2; ++kt) {
            bf16x8 av[2];
            #pragma unroll
            for (int mt = 0; mt < 2; ++mt)
                av[mt] = *(const bf16x8*)&vbt[(16*mt + c) * VBT_STR + 32*kt + 8*g];
            #pragma unroll
            for (int jj = 0; jj < 2; ++jj) {
                int qt = 16*(ntq0+jj) + c; if (qt > 48) qt = 48;
                bf16x8 bp2 = *(const bf16x8*)&pbh[qt * 72 + 32*kt + 8*g];
                #pragma unroll
                for (int mt = 0; mt < 2; ++mt)
                    o[mt][jj] = __builtin_amdgcn_mfma_f32_16x16x32_bf16(av[mt], bp2, o[mt][jj], 0, 0, 0);
            }
        }
        __builtin_amdgcn_s_setprio(0);
        // O_h[qtok][dim0..31] -> pbuf's OWN rows, cols 0..31 (no cross-wave readers until B4)
        #pragma unroll
        for (int jj = 0; jj < 2; ++jj) {
            int qtok = 16*(ntq0+jj) + c;
            if (qtok >= NTOK) continue;
            #pragma unroll
            for (int mt = 0; mt < 2; ++mt) {
                s16x4 pko;
                pko[0] = f2b(o[mt][jj][0]); pko[1] = f2b(o[mt][jj][1]);
                pko[2] = f2b(o[mt][jj][2]); pko[3] = f2b(o[mt][jj][3]);
                *(s16x4*)&pbh[qtok * 72 + 16*mt + 4*g] = pko;
            }
        }
    }
    __syncthreads();   // B4: O complete

    // ---------- phase 4: Y^T = Wp^T(128x128) @ O^T(128x49pad) ----------
    {
        const int chb = 16 * wv;
        f32x4 po[4];
        #pragma unroll
        for (int j = 0; j < 4; ++j) po[j] = (f32x4){0.f,0.f,0.f,0.f};
        #pragma unroll
        for (int kt = 0; kt < 4; ++kt) {
            bf16x8 aw = *(const bf16x8*)&wproj_t[(chb + c) * 128 + 32*kt + 8*g];
            const short* ob_kt = sm + RQK + kt * QK_SZ;   // O of head kt, stride 72, cols 0..31
            __builtin_amdgcn_s_setprio(1);
            #pragma unroll
            for (int j = 0; j < 4; ++j) {
                int qt = 16*j + c; if (qt > 48) qt = 48;
                bf16x8 bo = *(const bf16x8*)&ob_kt[qt * 72 + 8*g];
                po[j] = __builtin_amdgcn_mfma_f32_16x16x32_bf16(aw, bo, po[j], 0, 0, 0);
            }
            __builtin_amdgcn_s_setprio(0);
        }
        f32x4 pb4 = *(const f32x4*)&proj_b[chb + 4*g];
        float* op = out + (size_t)b * 6272;
        #pragma unroll
        for (int j = 0; j < 4; ++j) {
            int qtok = 16*j + c;
            if (qtok >= NTOK) continue;
            f32x4 w;
            w[0] = po[j][0] + pb4[0]; w[1] = po[j][1] + pb4[1];
            w[2] = po[j][2] + pb4[2]; w[3] = po[j][3] + pb4[3];
            *(f32x4*)&op[qtok * 128 + chb + 4*g] = w;
        }
    }
}

extern "C" void kernel_launch(void* const* d_in, const int* in_sizes, int n_in,
                              void* d_out, int out_size, void* d_ws, size_t ws_size,
                              hipStream_t stream) {
    const float* x       = (const float*)d_in[0];
    const float* qkv_w   = (const float*)d_in[1];
    const float* qkv_b   = (const float*)d_in[2];
    const float* proj_w  = (const float*)d_in[3];
    const float* proj_b  = (const float*)d_in[4];
    const float* rel_tab = (const float*)d_in[5];
    const int*   rel_idx = (const int*)d_in[7];

    char* ws = (char*)d_ws;
    short* wqkv_t  = (short*)ws;                        // 98304 B
    short* wproj_t = (short*)(ws + 98304);              // 32768 B
    float* bmp2    = (float*)(ws + 98304 + 32768);      // 16*49*64*4 = 200704 B

    int total = 384*128 + 128*128 + 16*NTOK*64;
    prep_kernel<<<(total + 255) / 256, 256, 0, stream>>>(qkv_w, proj_w, rel_tab, rel_idx,
                                                         wqkv_t, wproj_t, bmp2);

    int B_ = in_sizes[0] / (NTOK * 128);                // 4096
    swin_fused<<<B_, 512, 0, stream>>>(x, wqkv_t, qkv_b, wproj_t, proj_b, bmp2,
                                       (float*)d_out);
}

// Round 8
// 132.419 us; speedup vs baseline: 2.2571x; 2.2571x over previous
//
#include <hip/hip_runtime.h>
#include <hip/hip_bf16.h>

typedef __attribute__((ext_vector_type(8))) short bf16x8;
typedef __attribute__((ext_vector_type(4))) short s16x4;
typedef __attribute__((ext_vector_type(4))) float f32x4;

#define NTOK 49

// LDS (shorts), total 33088 = 66176 B -> 2 blocks/CU (register-limited anyway):
//  X   [0, 8704):      [64][136]  rows 49..63 zeroed once (static region)
//  vbt [8704, 17408):  head h at 8704+h*2176: V^T [32][68], toks 49..63 zeroed once
//  RQK [17408, 33088): head h at 17408+h*3920: q[49][40], k[49][40] at +1960
//      pbuf [49][72] overlays q+k after B3 (rows private per wave);
//      O_h[qtok][dim0..31] reuses pbuf rows, cols 0..31 (after own PV)
#define XROW    136
#define RVB     8704
#define VBT_STR 68
#define VBT_SZ  2176
#define RQK     17408
#define QK_SZ   3920
#define SM_TOT  33088

__device__ __forceinline__ short f2b(float v) {
    __hip_bfloat16 b = __float2bfloat16(v);
    return *reinterpret_cast<short*>(&b);
}

// region id: mask[w][i][j]==0 iff rid(i)==rid(j); slices [0,49)[49,53)[53,56)
__device__ __forceinline__ int rid_of(int t, int wh, int ww) {
    int i = t / 7;
    int j = t - 7 * i;
    int rh = (wh == 7) ? ((i < 4) ? 1 : 2) : 0;
    int rw = (ww == 7) ? ((j < 4) ? 1 : 2) : 0;
    return rh * 3 + rw;
}

__global__ void prep_kernel(const float* __restrict__ qkv_w,
                            const float* __restrict__ proj_w,
                            const float* __restrict__ rel_tab,
                            const int*   __restrict__ rel_idx,
                            short* __restrict__ wqkv_t,
                            short* __restrict__ wproj_t,
                            float* __restrict__ bmp2) {
    int i = blockIdx.x * 256 + threadIdx.x;
    if (i < 384 * 128) {               // wqkv_t[n][k] = qkv_w[k][n]
        int n = i >> 7, k = i & 127;
        wqkv_t[i] = f2b(qkv_w[k * 384 + n]);
        return;
    }
    int j = i - 384 * 128;
    if (j < 128 * 128) {               // wproj_t[n][k] = proj_w[k][n]
        int n = j >> 7, k = j & 127;
        wproj_t[j] = f2b(proj_w[k * 128 + n]);
        return;
    }
    int l = j - 128 * 128;
    if (l < 16 * NTOK * 64) {          // bmp2[wt][h][q][k64]: bias+mask, pad -1e30
        int wt  = l / (4 * NTOK * 64);
        int rem = l - wt * (4 * NTOK * 64);
        int h   = rem / (NTOK * 64);
        int rm2 = rem - h * (NTOK * 64);
        int q = rm2 >> 6, kk = rm2 & 63;
        float v;
        if (kk < NTOK) {
            v = rel_tab[rel_idx[q * NTOK + kk] * 4 + h];
            int wh = (wt & 1) ? 7 : 0, ww = (wt & 2) ? 7 : 0;
            if (rid_of(q, wh, ww) != rid_of(kk, wh, ww)) v -= 100.0f;
        } else {
            v = -1e30f;
        }
        bmp2[l] = v;
    }
}

__launch_bounds__(512, 4)
__global__ void swin_fused(const float* __restrict__ x,
                           const short* __restrict__ wqkv_t,
                           const float* __restrict__ qkv_b,
                           const short* __restrict__ wproj_t,
                           const float* __restrict__ proj_b,
                           const float* __restrict__ bmp2,
                           float* __restrict__ out) {
    __shared__ short sm[SM_TOT];

    const int b   = blockIdx.x;
    const int tid = threadIdx.x;
    const int wv  = tid >> 6;
    const int ln  = tid & 63;
    const int g   = ln >> 4;
    const int c   = ln & 15;
    const int h    = wv >> 1;
    const int half = wv & 1;

    short* vbt = sm + RVB + h * VBT_SZ;      // [32][68]
    short* qbh = sm + RQK + h * QK_SZ;       // [49][40]
    short* kbh = qbh + 1960;                 // [49][40]
    short* pbh = qbh;                        // [49][72] overlay (post-B3); O in cols 0..31

    // ---------- phase 0: zero pads (X rows 49..63, vbt toks 49..63) + stage X ----------
    if (tid < 510) {                         // 2040 shorts = 510 x 8B
        *(s16x4*)&sm[NTOK * XROW + tid * 4] = (s16x4){0, 0, 0, 0};
    }
    for (int idx = tid; idx < 128 * 15; idx += 512) {
        int d = idx / 15, t = 49 + (idx - (idx / 15) * 15);
        sm[RVB + (d >> 5) * VBT_SZ + (d & 31) * VBT_STR + t] = 0;
    }
    {
        const f32x4* xp4 = (const f32x4*)(x + (size_t)b * 6272);
        f32x4 v0 = xp4[tid];
        f32x4 v1 = xp4[tid + 512];
        f32x4 v2 = xp4[tid + 1024];
        f32x4 v3;
        if (tid < 32) v3 = xp4[tid + 1536];
        #define XWR(IDX, V) { int row = (IDX) >> 5; int col = ((IDX) & 31) * 4; \
            s16x4 pk; pk[0]=f2b((V)[0]); pk[1]=f2b((V)[1]); pk[2]=f2b((V)[2]); pk[3]=f2b((V)[3]); \
            *(s16x4*)&sm[row * XROW + col] = pk; }
        XWR(tid, v0) XWR(tid + 512, v1) XWR(tid + 1024, v2)
        if (tid < 32) XWR(tid + 1536, v3)
        #undef XWR
    }
    __syncthreads();   // B1: X (incl. zero pad rows) ready

    const int cq = 32 * h + 16 * half;       // wave's 16-channel base

    // ---------- phase 1a: Q,K channels [cq,cq+16) ----------
    {
        f32x4 accq[4], acck[4];
        #pragma unroll
        for (int nt = 0; nt < 4; ++nt) { accq[nt] = (f32x4){0.f,0.f,0.f,0.f}; acck[nt] = (f32x4){0.f,0.f,0.f,0.f}; }
        #pragma unroll
        for (int kt = 0; kt < 4; ++kt) {
            bf16x8 awq = *(const bf16x8*)&wqkv_t[(cq + c) * 128 + 32*kt + 8*g];
            bf16x8 awk = *(const bf16x8*)&wqkv_t[(128 + cq + c) * 128 + 32*kt + 8*g];
            bf16x8 xv[4];
            #pragma unroll
            for (int nt = 0; nt < 4; ++nt)
                xv[nt] = *(const bf16x8*)&sm[(16*nt + c) * XROW + 32*kt + 8*g];
            __builtin_amdgcn_s_setprio(1);
            #pragma unroll
            for (int nt = 0; nt < 4; ++nt) {
                accq[nt] = __builtin_amdgcn_mfma_f32_16x16x32_bf16(awq, xv[nt], accq[nt], 0, 0, 0);
                acck[nt] = __builtin_amdgcn_mfma_f32_16x16x32_bf16(awk, xv[nt], acck[nt], 0, 0, 0);
            }
            __builtin_amdgcn_s_setprio(0);
        }
        const float qsc = 0.17677669529663687f;   // 32^-0.5 folded into q
        f32x4 bq4 = *(const f32x4*)&qkv_b[cq + 4*g];
        f32x4 bk4 = *(const f32x4*)&qkv_b[128 + cq + 4*g];
        #pragma unroll
        for (int nt = 0; nt < 4; ++nt) {
            int tok = 16*nt + c;
            if (tok >= NTOK) continue;
            s16x4 pq, pk2;
            #pragma unroll
            for (int r = 0; r < 4; ++r) {
                pq[r]  = f2b((accq[nt][r] + bq4[r]) * qsc);
                pk2[r] = f2b(acck[nt][r] + bk4[r]);
            }
            *(s16x4*)&qbh[tok * 40 + 16*half + 4*g] = pq;
            *(s16x4*)&kbh[tok * 40 + 16*half + 4*g] = pk2;
        }
    }

    // ---------- phase 1b: V channels -> vbt (stride 68: conflict-free scatter) ----------
    {
        f32x4 accv[4];
        #pragma unroll
        for (int nt = 0; nt < 4; ++nt) accv[nt] = (f32x4){0.f,0.f,0.f,0.f};
        #pragma unroll
        for (int kt = 0; kt < 4; ++kt) {
            bf16x8 awv = *(const bf16x8*)&wqkv_t[(256 + cq + c) * 128 + 32*kt + 8*g];
            bf16x8 xv[4];
            #pragma unroll
            for (int nt = 0; nt < 4; ++nt)
                xv[nt] = *(const bf16x8*)&sm[(16*nt + c) * XROW + 32*kt + 8*g];
            __builtin_amdgcn_s_setprio(1);
            #pragma unroll
            for (int nt = 0; nt < 4; ++nt)
                accv[nt] = __builtin_amdgcn_mfma_f32_16x16x32_bf16(awv, xv[nt], accv[nt], 0, 0, 0);
            __builtin_amdgcn_s_setprio(0);
        }
        f32x4 bv4 = *(const f32x4*)&qkv_b[256 + cq + 4*g];
        const int d0 = 16*half + 4*g;
        #pragma unroll
        for (int nt = 0; nt < 4; ++nt) {
            int tok = 16*nt + c;
            if (tok >= NTOK) continue;
            vbt[(d0+0) * VBT_STR + tok] = f2b(accv[nt][0] + bv4[0]);
            vbt[(d0+1) * VBT_STR + tok] = f2b(accv[nt][1] + bv4[1]);
            vbt[(d0+2) * VBT_STR + tok] = f2b(accv[nt][2] + bv4[2]);
            vbt[(d0+3) * VBT_STR + tok] = f2b(accv[nt][3] + bv4[3]);
        }
    }
    __syncthreads();   // B2: q,k,v^T ready

    // ---------- phase 2: bias prefetch + S^T = K(64x32) @ Q^T(32x64) ----------
    const int ntq0 = 2 * half;
    const int wt = ((((b >> 3) & 7) == 7) ? 1 : 0) | (((b & 7) == 7) ? 2 : 0);
    const float* bbase = bmp2 + ((size_t)(wt * 4 + h) * NTOK) * 64;
    f32x4 bias0[4], bias1[4];
    {
        int q0c = 16*ntq0 + c;       if (q0c > 48) q0c = 48;
        int q1c = 16*(ntq0+1) + c;   if (q1c > 48) q1c = 48;
        const float* bp0 = bbase + (size_t)q0c * 64;
        const float* bp1 = bbase + (size_t)q1c * 64;
        #pragma unroll
        for (int mt = 0; mt < 4; ++mt) {
            bias0[mt] = *(const f32x4*)&bp0[16*mt + 4*g];
            bias1[mt] = *(const f32x4*)&bp1[16*mt + 4*g];
        }
    }
    f32x4 sA[4][2];
    {
        #pragma unroll
        for (int mt = 0; mt < 4; ++mt) { sA[mt][0] = (f32x4){0.f,0.f,0.f,0.f}; sA[mt][1] = (f32x4){0.f,0.f,0.f,0.f}; }
        bf16x8 ak[4];
        #pragma unroll
        for (int mt = 0; mt < 4; ++mt) {
            int kt2 = 16*mt + c; if (kt2 > 48) kt2 = 48;
            ak[mt] = *(const bf16x8*)&kbh[kt2 * 40 + 8*g];
        }
        __builtin_amdgcn_s_setprio(1);
        #pragma unroll
        for (int jj = 0; jj < 2; ++jj) {
            int qt = 16*(ntq0+jj) + c; if (qt > 48) qt = 48;
            bf16x8 bq = *(const bf16x8*)&qbh[qt * 40 + 8*g];
            #pragma unroll
            for (int mt = 0; mt < 4; ++mt)
                sA[mt][jj] = __builtin_amdgcn_mfma_f32_16x16x32_bf16(ak[mt], bq, sA[mt][jj], 0, 0, 0);
        }
        __builtin_amdgcn_s_setprio(0);
    }
    __syncthreads();   // B3: q,k fragments consumed; pbuf may overlay

    // ---------- softmax (bias+mask pre-fused) + P -> pbuf + PV + O -> pbuf cols 0..31 ----------
    {
        #pragma unroll
        for (int jj = 0; jj < 2; ++jj) {
            int qtok = 16*(ntq0+jj) + c;
            const f32x4* bias = jj ? bias1 : bias0;
            float e[16];
            float mx = -1e30f;
            #pragma unroll
            for (int mt = 0; mt < 4; ++mt) {
                #pragma unroll
                for (int r = 0; r < 4; ++r) {
                    float v = sA[mt][jj][r] + bias[mt][r];
                    e[4*mt+r] = v;
                    mx = fmaxf(mx, v);
                }
            }
            mx = fmaxf(mx, __shfl_xor(mx, 16, 64));
            mx = fmaxf(mx, __shfl_xor(mx, 32, 64));
            float s = 0.f;
            #pragma unroll
            for (int ii = 0; ii < 16; ++ii) { float ev = __expf(e[ii] - mx); e[ii] = ev; s += ev; }
            s += __shfl_xor(s, 16, 64);
            s += __shfl_xor(s, 32, 64);
            float rs = 1.0f / s;
            if (qtok < NTOK) {
                #pragma unroll
                for (int mt = 0; mt < 4; ++mt) {
                    s16x4 pk;
                    pk[0] = f2b(e[4*mt+0] * rs);
                    pk[1] = f2b(e[4*mt+1] * rs);
                    pk[2] = f2b(e[4*mt+2] * rs);
                    pk[3] = f2b(e[4*mt+3] * rs);
                    *(s16x4*)&pbh[qtok * 72 + 16*mt + 4*g] = pk;
                }
            }
        }

        // PV: O^T = V^T(32x64) @ P^T(64x64); P pad rows (k>=49) got -1e30 bias -> 0
        f32x4 o[2][2];
        o[0][0]=(f32x4){0.f,0.f,0.f,0.f}; o[0][1]=(f32x4){0.f,0.f,0.f,0.f};
        o[1][0]=(f32x4){0.f,0.f,0.f,0.f}; o[1][1]=(f32x4){0.f,0.f,0.f,0.f};
        __builtin_amdgcn_s_setprio(1);
        #pragma unroll
        for (int kt = 0; kt < 2; ++kt) {
            bf16x8 av[2];
            #pragma unroll
            for (int mt = 0; mt < 2; ++mt)
                av[mt] = *(const bf16x8*)&vbt[(16*mt + c) * VBT_STR + 32*kt + 8*g];
            #pragma unroll
            for (int jj = 0; jj < 2; ++jj) {
                int qt = 16*(ntq0+jj) + c; if (qt > 48) qt = 48;
                bf16x8 bp2 = *(const bf16x8*)&pbh[qt * 72 + 32*kt + 8*g];
                #pragma unroll
                for (int mt = 0; mt < 2; ++mt)
                    o[mt][jj] = __builtin_amdgcn_mfma_f32_16x16x32_bf16(av[mt], bp2, o[mt][jj], 0, 0, 0);
            }
        }
        __builtin_amdgcn_s_setprio(0);
        // O_h[qtok][dim0..31] -> pbuf's OWN rows, cols 0..31
        #pragma unroll
        for (int jj = 0; jj < 2; ++jj) {
            int qtok = 16*(ntq0+jj) + c;
            if (qtok >= NTOK) continue;
            #pragma unroll
            for (int mt = 0; mt < 2; ++mt) {
                s16x4 pko;
                pko[0] = f2b(o[mt][jj][0]); pko[1] = f2b(o[mt][jj][1]);
                pko[2] = f2b(o[mt][jj][2]); pko[3] = f2b(o[mt][jj][3]);
                *(s16x4*)&pbh[qtok * 72 + 16*mt + 4*g] = pko;
            }
        }
    }
    __syncthreads();   // B4: O complete

    // ---------- phase 4: Y^T = Wp^T(128x128) @ O^T(128x49pad) ----------
    {
        const int chb = 16 * wv;
        f32x4 po[4];
        #pragma unroll
        for (int j = 0; j < 4; ++j) po[j] = (f32x4){0.f,0.f,0.f,0.f};
        #pragma unroll
        for (int kt = 0; kt < 4; ++kt) {
            bf16x8 aw = *(const bf16x8*)&wproj_t[(chb + c) * 128 + 32*kt + 8*g];
            const short* ob_kt = sm + RQK + kt * QK_SZ;   // O of head kt (stride 72, cols 0..31)
            __builtin_amdgcn_s_setprio(1);
            #pragma unroll
            for (int j = 0; j < 4; ++j) {
                int qt = 16*j + c; if (qt > 48) qt = 48;
                bf16x8 bo = *(const bf16x8*)&ob_kt[qt * 72 + 8*g];
                po[j] = __builtin_amdgcn_mfma_f32_16x16x32_bf16(aw, bo, po[j], 0, 0, 0);
            }
            __builtin_amdgcn_s_setprio(0);
        }
        f32x4 pb4 = *(const f32x4*)&proj_b[chb + 4*g];
        float* op = out + (size_t)b * 6272;
        #pragma unroll
        for (int j = 0; j < 4; ++j) {
            int qtok = 16*j + c;
            if (qtok >= NTOK) continue;
            f32x4 w;
            w[0] = po[j][0] + pb4[0]; w[1] = po[j][1] + pb4[1];
            w[2] = po[j][2] + pb4[2]; w[3] = po[j][3] + pb4[3];
            *(f32x4*)&op[qtok * 128 + chb + 4*g] = w;
        }
    }
}

extern "C" void kernel_launch(void* const* d_in, const int* in_sizes, int n_in,
                              void* d_out, int out_size, void* d_ws, size_t ws_size,
                              hipStream_t stream) {
    const float* x       = (const float*)d_in[0];
    const float* qkv_w   = (const float*)d_in[1];
    const float* qkv_b   = (const float*)d_in[2];
    const float* proj_w  = (const float*)d_in[3];
    const float* proj_b  = (const float*)d_in[4];
    const float* rel_tab = (const float*)d_in[5];
    const int*   rel_idx = (const int*)d_in[7];

    char* ws = (char*)d_ws;
    short* wqkv_t  = (short*)ws;                        // 98304 B
    short* wproj_t = (short*)(ws + 98304);              // 32768 B
    float* bmp2    = (float*)(ws + 98304 + 32768);      // 200704 B

    int total = 384*128 + 128*128 + 16*NTOK*64;
    prep_kernel<<<(total + 255) / 256, 256, 0, stream>>>(qkv_w, proj_w, rel_tab, rel_idx,
                                                         wqkv_t, wproj_t, bmp2);

    int B_ = in_sizes[0] / (NTOK * 128);                // 4096
    swin_fused<<<B_, 512, 0, stream>>>(x, wqkv_t, qkv_b, wproj_t, proj_b, bmp2,
                                       (float*)d_out);
}

// Round 10
// 129.437 us; speedup vs baseline: 2.3091x; 1.0230x over previous
//
#include <hip/hip_runtime.h>
#include <hip/hip_bf16.h>

typedef __attribute__((ext_vector_type(8))) short bf16x8;
typedef __attribute__((ext_vector_type(4))) short s16x4;
typedef __attribute__((ext_vector_type(4))) float f32x4;

#define NTOK 49

// LDS (shorts), total 33088 = 66176 B -> 2 blocks/CU:
//  X   [0, 8704):      [64][136]  rows 49..63 zeroed once (static region)
//  vbt [8704, 17408):  head h at 8704+h*2176: V^T [32][68], toks 49..63 zeroed once
//  RQK [17408, 33088): head h at 17408+h*3920: q[49][40], k[49][40] at +1960
//      pbuf [49][72] overlays q+k after B3 (rows private per wave);
//      O_h[qtok][dim0..31] reuses pbuf rows, cols 0..31 (after own PV)
#define XROW    136
#define RVB     8704
#define VBT_STR 68
#define VBT_SZ  2176
#define RQK     17408
#define QK_SZ   3920
#define SM_TOT  33088

__device__ __forceinline__ short f2b(float v) {
    __hip_bfloat16 b = __float2bfloat16(v);
    return *reinterpret_cast<short*>(&b);
}

// region id: mask[w][i][j]==0 iff rid(i)==rid(j); slices [0,49)[49,53)[53,56)
__device__ __forceinline__ int rid_of(int t, int wh, int ww) {
    int i = t / 7;
    int j = t - 7 * i;
    int rh = (wh == 7) ? ((i < 4) ? 1 : 2) : 0;
    int rw = (ww == 7) ? ((j < 4) ? 1 : 2) : 0;
    return rh * 3 + rw;
}

__global__ void prep_kernel(const float* __restrict__ qkv_w,
                            const float* __restrict__ proj_w,
                            const float* __restrict__ rel_tab,
                            const int*   __restrict__ rel_idx,
                            short* __restrict__ wqkv_t,
                            short* __restrict__ wproj_t,
                            float* __restrict__ bmp2) {
    int i = blockIdx.x * 256 + threadIdx.x;
    if (i < 384 * 128) {               // wqkv_t[n][k] = qkv_w[k][n]
        int n = i >> 7, k = i & 127;
        wqkv_t[i] = f2b(qkv_w[k * 384 + n]);
        return;
    }
    int j = i - 384 * 128;
    if (j < 128 * 128) {               // wproj_t[n][k] = proj_w[k][n]
        int n = j >> 7, k = j & 127;
        wproj_t[j] = f2b(proj_w[k * 128 + n]);
        return;
    }
    int l = j - 128 * 128;
    if (l < 16 * NTOK * 64) {          // bmp2[wt][h][q][k64]: (bias+mask)*log2e, pad -1e30
        const float LOG2E = 1.4426950408889634f;
        int wt  = l / (4 * NTOK * 64);
        int rem = l - wt * (4 * NTOK * 64);
        int h   = rem / (NTOK * 64);
        int rm2 = rem - h * (NTOK * 64);
        int q = rm2 >> 6, kk = rm2 & 63;
        float v;
        if (kk < NTOK) {
            v = rel_tab[rel_idx[q * NTOK + kk] * 4 + h] * LOG2E;
            int wh = (wt & 1) ? 7 : 0, ww = (wt & 2) ? 7 : 0;
            if (rid_of(q, wh, ww) != rid_of(kk, wh, ww)) v -= 100.0f * LOG2E;
        } else {
            v = -1e30f;
        }
        bmp2[l] = v;
    }
}

__launch_bounds__(512, 4)
__global__ void swin_fused(const float* __restrict__ x,
                           const short* __restrict__ wqkv_t,
                           const float* __restrict__ qkv_b,
                           const short* __restrict__ wproj_t,
                           const float* __restrict__ proj_b,
                           const float* __restrict__ bmp2,
                           float* __restrict__ out) {
    __shared__ short sm[SM_TOT];

    const int b   = blockIdx.x;
    const int tid = threadIdx.x;
    const int wv  = tid >> 6;
    const int ln  = tid & 63;
    const int g   = ln >> 4;
    const int c   = ln & 15;
    const int h    = wv >> 1;
    const int half = wv & 1;

    short* vbt = sm + RVB + h * VBT_SZ;      // [32][68]
    short* qbh = sm + RQK + h * QK_SZ;       // [49][40]
    short* kbh = qbh + 1960;                 // [49][40]
    short* pbh = qbh;                        // [49][72] overlay (post-B3); O in cols 0..31

    const int cq = 32 * h + 16 * half;       // wave's 16-channel base

    // ---------- phase 0: zero pads + stage X; then issue phase-1a weight loads ----------
    if (tid < 510) {
        *(s16x4*)&sm[NTOK * XROW + tid * 4] = (s16x4){0, 0, 0, 0};
    }
    for (int idx = tid; idx < 128 * 15; idx += 512) {
        int d = idx / 15, t = 49 + (idx - (idx / 15) * 15);
        sm[RVB + (d >> 5) * VBT_SZ + (d & 31) * VBT_STR + t] = 0;
    }
    {
        const f32x4* xp4 = (const f32x4*)(x + (size_t)b * 6272);
        f32x4 v0 = xp4[tid];
        f32x4 v1 = xp4[tid + 512];
        f32x4 v2 = xp4[tid + 1024];
        f32x4 v3;
        if (tid < 32) v3 = xp4[tid + 1536];
        #define XWR(IDX, V) { int row = (IDX) >> 5; int col = ((IDX) & 31) * 4; \
            s16x4 pk; pk[0]=f2b((V)[0]); pk[1]=f2b((V)[1]); pk[2]=f2b((V)[2]); pk[3]=f2b((V)[3]); \
            *(s16x4*)&sm[row * XROW + col] = pk; }
        XWR(tid, v0) XWR(tid + 512, v1) XWR(tid + 1024, v2)
        if (tid < 32) XWR(tid + 1536, v3)
        #undef XWR
    }
    // preload phase-1a weights; vmcnt drain piggybacks on B1's barrier drain
    bf16x8 wqr[4], wkr[4];
    #pragma unroll
    for (int kt = 0; kt < 4; ++kt) {
        wqr[kt] = *(const bf16x8*)&wqkv_t[(cq + c) * 128 + 32*kt + 8*g];
        wkr[kt] = *(const bf16x8*)&wqkv_t[(128 + cq + c) * 128 + 32*kt + 8*g];
    }
    __syncthreads();   // B1: X (incl. zero pad rows) ready

    // ---------- phase 1a: Q,K channels [cq,cq+16) ----------
    bf16x8 wvr[4];
    {
        f32x4 accq[4], acck[4];
        #pragma unroll
        for (int nt = 0; nt < 4; ++nt) { accq[nt] = (f32x4){0.f,0.f,0.f,0.f}; acck[nt] = (f32x4){0.f,0.f,0.f,0.f}; }
        #pragma unroll
        for (int kt = 0; kt < 4; ++kt) {
            bf16x8 xv[4];
            #pragma unroll
            for (int nt = 0; nt < 4; ++nt)
                xv[nt] = *(const bf16x8*)&sm[(16*nt + c) * XROW + 32*kt + 8*g];
            #pragma unroll
            for (int nt = 0; nt < 4; ++nt) {
                accq[nt] = __builtin_amdgcn_mfma_f32_16x16x32_bf16(wqr[kt], xv[nt], accq[nt], 0, 0, 0);
                acck[nt] = __builtin_amdgcn_mfma_f32_16x16x32_bf16(wkr[kt], xv[nt], acck[nt], 0, 0, 0);
            }
        }
        // issue phase-1b weight loads; latency hides under the epilogue below
        #pragma unroll
        for (int kt = 0; kt < 4; ++kt)
            wvr[kt] = *(const bf16x8*)&wqkv_t[(256 + cq + c) * 128 + 32*kt + 8*g];

        const float qsc = 0.17677669529663687f * 1.4426950408889634f;  // 32^-0.5 * log2e
        f32x4 bq4 = *(const f32x4*)&qkv_b[cq + 4*g];
        f32x4 bk4 = *(const f32x4*)&qkv_b[128 + cq + 4*g];
        #pragma unroll
        for (int nt = 0; nt < 4; ++nt) {
            int tok = 16*nt + c;
            if (tok >= NTOK) continue;
            s16x4 pq, pk2;
            #pragma unroll
            for (int r = 0; r < 4; ++r) {
                pq[r]  = f2b((accq[nt][r] + bq4[r]) * qsc);
                pk2[r] = f2b(acck[nt][r] + bk4[r]);
            }
            *(s16x4*)&qbh[tok * 40 + 16*half + 4*g] = pq;
            *(s16x4*)&kbh[tok * 40 + 16*half + 4*g] = pk2;
        }
    }

    // ---------- phase 1b: V channels -> vbt ----------
    {
        f32x4 accv[4];
        #pragma unroll
        for (int nt = 0; nt < 4; ++nt) accv[nt] = (f32x4){0.f,0.f,0.f,0.f};
        #pragma unroll
        for (int kt = 0; kt < 4; ++kt) {
            bf16x8 xv[4];
            #pragma unroll
            for (int nt = 0; nt < 4; ++nt)
                xv[nt] = *(const bf16x8*)&sm[(16*nt + c) * XROW + 32*kt + 8*g];
            #pragma unroll
            for (int nt = 0; nt < 4; ++nt)
                accv[nt] = __builtin_amdgcn_mfma_f32_16x16x32_bf16(wvr[kt], xv[nt], accv[nt], 0, 0, 0);
        }
        f32x4 bv4 = *(const f32x4*)&qkv_b[256 + cq + 4*g];
        const int d0 = 16*half + 4*g;
        #pragma unroll
        for (int nt = 0; nt < 4; ++nt) {
            int tok = 16*nt + c;
            if (tok >= NTOK) continue;
            vbt[(d0+0) * VBT_STR + tok] = f2b(accv[nt][0] + bv4[0]);
            vbt[(d0+1) * VBT_STR + tok] = f2b(accv[nt][1] + bv4[1]);
            vbt[(d0+2) * VBT_STR + tok] = f2b(accv[nt][2] + bv4[2]);
            vbt[(d0+3) * VBT_STR + tok] = f2b(accv[nt][3] + bv4[3]);
        }
    }

    // bias prefetch issued before B2; consumed after B3 (long slack)
    const int ntq0 = 2 * half;
    const int wt = ((((b >> 3) & 7) == 7) ? 1 : 0) | (((b & 7) == 7) ? 2 : 0);
    const float* bbase = bmp2 + ((size_t)(wt * 4 + h) * NTOK) * 64;
    f32x4 bias0[4], bias1[4];
    {
        int q0c = 16*ntq0 + c;       if (q0c > 48) q0c = 48;
        int q1c = 16*(ntq0+1) + c;   if (q1c > 48) q1c = 48;
        const float* bp0 = bbase + (size_t)q0c * 64;
        const float* bp1 = bbase + (size_t)q1c * 64;
        #pragma unroll
        for (int mt = 0; mt < 4; ++mt) {
            bias0[mt] = *(const f32x4*)&bp0[16*mt + 4*g];
            bias1[mt] = *(const f32x4*)&bp1[16*mt + 4*g];
        }
    }
    __syncthreads();   // B2: q,k,v^T ready

    // ---------- phase 2: S^T = K(64x32) @ Q^T(32x64) ----------
    f32x4 sA[4][2];
    {
        #pragma unroll
        for (int mt = 0; mt < 4; ++mt) { sA[mt][0] = (f32x4){0.f,0.f,0.f,0.f}; sA[mt][1] = (f32x4){0.f,0.f,0.f,0.f}; }
        bf16x8 ak[4];
        #pragma unroll
        for (int mt = 0; mt < 4; ++mt) {
            int kt2 = 16*mt + c; if (kt2 > 48) kt2 = 48;
            ak[mt] = *(const bf16x8*)&kbh[kt2 * 40 + 8*g];
        }
        #pragma unroll
        for (int jj = 0; jj < 2; ++jj) {
            int qt = 16*(ntq0+jj) + c; if (qt > 48) qt = 48;
            bf16x8 bq = *(const bf16x8*)&qbh[qt * 40 + 8*g];
            #pragma unroll
            for (int mt = 0; mt < 4; ++mt)
                sA[mt][jj] = __builtin_amdgcn_mfma_f32_16x16x32_bf16(ak[mt], bq, sA[mt][jj], 0, 0, 0);
        }
    }
    __syncthreads();   // B3: q,k fragments consumed; pbuf may overlay

    // ---------- softmax (log2 domain, unnormalized P) + PV + O -> pbuf cols 0..31 ----------
    {
        float rs01[2];
        #pragma unroll
        for (int jj = 0; jj < 2; ++jj) {
            int qtok = 16*(ntq0+jj) + c;
            const f32x4* bias = jj ? bias1 : bias0;
            float e[16];
            float mx = -1e30f;
            #pragma unroll
            for (int mt = 0; mt < 4; ++mt) {
                #pragma unroll
                for (int r = 0; r < 4; ++r) {
                    float v = sA[mt][jj][r] + bias[mt][r];
                    e[4*mt+r] = v;
                    mx = fmaxf(mx, v);
                }
            }
            mx = fmaxf(mx, __shfl_xor(mx, 16, 64));
            mx = fmaxf(mx, __shfl_xor(mx, 32, 64));
            float s = 0.f;
            #pragma unroll
            for (int ii = 0; ii < 16; ++ii) { float ev = exp2f(e[ii] - mx); e[ii] = ev; s += ev; }
            // write unnormalized P immediately (shortest path to PV)
            if (qtok < NTOK) {
                #pragma unroll
                for (int mt = 0; mt < 4; ++mt) {
                    s16x4 pk;
                    pk[0] = f2b(e[4*mt+0]);
                    pk[1] = f2b(e[4*mt+1]);
                    pk[2] = f2b(e[4*mt+2]);
                    pk[3] = f2b(e[4*mt+3]);
                    *(s16x4*)&pbh[qtok * 72 + 16*mt + 4*g] = pk;
                }
            }
            // finish the sum concurrently with P writes
            s += __shfl_xor(s, 16, 64);
            s += __shfl_xor(s, 32, 64);
            rs01[jj] = 1.0f / s;
        }

        // PV: O^T = V^T(32x64) @ P^T(64x64); P pad rows (k>=49) got -1e30 bias -> 0
        f32x4 o[2][2];
        o[0][0]=(f32x4){0.f,0.f,0.f,0.f}; o[0][1]=(f32x4){0.f,0.f,0.f,0.f};
        o[1][0]=(f32x4){0.f,0.f,0.f,0.f}; o[1][1]=(f32x4){0.f,0.f,0.f,0.f};
        #pragma unroll
        for (int kt = 0; kt < 2; ++kt) {
            bf16x8 av[2];
            #pragma unroll
            for (int mt = 0; mt < 2; ++mt)
                av[mt] = *(const bf16x8*)&vbt[(16*mt + c) * VBT_STR + 32*kt + 8*g];
            #pragma unroll
            for (int jj = 0; jj < 2; ++jj) {
                int qt = 16*(ntq0+jj) + c; if (qt > 48) qt = 48;
                bf16x8 bp2 = *(const bf16x8*)&pbh[qt * 72 + 32*kt + 8*g];
                #pragma unroll
                for (int mt = 0; mt < 2; ++mt)
                    o[mt][jj] = __builtin_amdgcn_mfma_f32_16x16x32_bf16(av[mt], bp2, o[mt][jj], 0, 0, 0);
            }
        }
        // O_h[qtok][dim0..31] -> pbuf's OWN rows, cols 0..31 (normalize here by rs)
        #pragma unroll
        for (int jj = 0; jj < 2; ++jj) {
            int qtok = 16*(ntq0+jj) + c;
            if (qtok >= NTOK) continue;
            float rs = rs01[jj];
            #pragma unroll
            for (int mt = 0; mt < 2; ++mt) {
                s16x4 pko;
                pko[0] = f2b(o[mt][jj][0] * rs); pko[1] = f2b(o[mt][jj][1] * rs);
                pko[2] = f2b(o[mt][jj][2] * rs); pko[3] = f2b(o[mt][jj][3] * rs);
                *(s16x4*)&pbh[qtok * 72 + 16*mt + 4*g] = pko;
            }
        }
    }
    __syncthreads();   // B4: O complete

    // ---------- phase 4: Y^T = Wp^T(128x128) @ O^T(128x49pad) ----------
    {
        const int chb = 16 * wv;
        // preload all 4 weight frags + bias up-front (regs are free here)
        bf16x8 awr[4];
        #pragma unroll
        for (int kt = 0; kt < 4; ++kt)
            awr[kt] = *(const bf16x8*)&wproj_t[(chb + c) * 128 + 32*kt + 8*g];
        f32x4 pb4 = *(const f32x4*)&proj_b[chb + 4*g];
        f32x4 po[4];
        #pragma unroll
        for (int j = 0; j < 4; ++j) po[j] = (f32x4){0.f,0.f,0.f,0.f};
        #pragma unroll
        for (int kt = 0; kt < 4; ++kt) {
            const short* ob_kt = sm + RQK + kt * QK_SZ;   // O of head kt (stride 72, cols 0..31)
            #pragma unroll
            for (int j = 0; j < 4; ++j) {
                int qt = 16*j + c; if (qt > 48) qt = 48;
                bf16x8 bo = *(const bf16x8*)&ob_kt[qt * 72 + 8*g];
                po[j] = __builtin_amdgcn_mfma_f32_16x16x32_bf16(awr[kt], bo, po[j], 0, 0, 0);
            }
        }
        float* op = out + (size_t)b * 6272;
        #pragma unroll
        for (int j = 0; j < 4; ++j) {
            int qtok = 16*j + c;
            if (qtok >= NTOK) continue;
            f32x4 w;
            w[0] = po[j][0] + pb4[0]; w[1] = po[j][1] + pb4[1];
            w[2] = po[j][2] + pb4[2]; w[3] = po[j][3] + pb4[3];
            *(f32x4*)&op[qtok * 128 + chb + 4*g] = w;
        }
    }
}

extern "C" void kernel_launch(void* const* d_in, const int* in_sizes, int n_in,
                              void* d_out, int out_size, void* d_ws, size_t ws_size,
                              hipStream_t stream) {
    const float* x       = (const float*)d_in[0];
    const float* qkv_w   = (const float*)d_in[1];
    const float* qkv_b   = (const float*)d_in[2];
    const float* proj_w  = (const float*)d_in[3];
    const float* proj_b  = (const float*)d_in[4];
    const float* rel_tab = (const float*)d_in[5];
    const int*   rel_idx = (const int*)d_in[7];

    char* ws = (char*)d_ws;
    short* wqkv_t  = (short*)ws;                        // 98304 B
    short* wproj_t = (short*)(ws + 98304);              // 32768 B
    float* bmp2    = (float*)(ws + 98304 + 32768);      // 200704 B

    int total = 384*128 + 128*128 + 16*NTOK*64;
    prep_kernel<<<(total + 255) / 256, 256, 0, stream>>>(qkv_w, proj_w, rel_tab, rel_idx,
                                                         wqkv_t, wproj_t, bmp2);

    int B_ = in_sizes[0] / (NTOK * 128);                // 4096
    swin_fused<<<B_, 512, 0, stream>>>(x, wqkv_t, qkv_b, wproj_t, proj_b, bmp2,
                                       (float*)d_out);
}